// Round 11
// baseline (532.824 us; speedup 1.0000x reference)
//
#include <hip/hip_runtime.h>

// MHAttention B=8 T=2048 C=512 H=512, causal, fp32 in/out.
// cast(fp32->fp16) -> fused QKV GEMM (Q row-major; K,V in MFMA-frag order) -> flash.
// R11 flash: persistent work-queue. 512 WGs x 4 waves, 43KB LDS (2+ per CU);
// global atomic ticket -> (batch, 32-row q-tile), longest-first. Per-tile body
// = R8's verified 4-wave structure (KVBLK=128, frag-order K/V, per-lane
// softmax) + R10's masked-strip skip. Fixes R7's 47% load imbalance and
// gives cross-WG barrier overlap without any register pressure.

using short8 = __attribute__((ext_vector_type(8))) short;
using half8  = __attribute__((ext_vector_type(8))) _Float16;
using f32x4  = __attribute__((ext_vector_type(4))) float;
using f32x16 = __attribute__((ext_vector_type(16))) float;

#define B_    8
#define T_    2048
#define SCALE_ 0.044194173824159216f   // 512^-0.5
#define NTILE 512                       // 64 tiles x 8 batches

// flash LDS: Q [32 rows][1KB] f16 (16B-granule XOR row&31) at 0
#define FL_P    32768    // [32 q][256B] f16 (granule XOR row&7), single buffer
#define FL_STX  40960    // 2 x [32 q][4 ks] f32 (step-parity)
#define FL_STS  41984    // 2 x [32 q][4 ks] f32
#define FL_TKT  43008    // int ticket
#define FL_SMEM 43072
// epilogue scratch reuses Q region (per wave 32 x 144B at wv*4608, <=18KB)

__device__ __forceinline__ void gload_lds16(const void* g, void* l) {
  __builtin_amdgcn_global_load_lds(
      (const __attribute__((address_space(1))) unsigned int*)g,
      (__attribute__((address_space(3))) unsigned int*)l, 16, 0, 0);
}

__device__ __forceinline__ unsigned short f2h(float f) {  // RNE f32->f16 bits
  _Float16 h = (_Float16)f;
  return *(unsigned short*)&h;
}

// barrier waiting only on LDS ops — global loads (vmcnt) stay in flight
__device__ __forceinline__ void barrier_lgkm() {
  asm volatile("s_waitcnt lgkmcnt(0)" ::: "memory");
  __builtin_amdgcn_s_barrier();
  asm volatile("" ::: "memory");
}

// ---------------------------------------------------------------- cast kernel
__global__ __launch_bounds__(256) void cast_kernel(
    const float* __restrict__ x, const float* __restrict__ wq,
    const float* __restrict__ wk, const float* __restrict__ wv,
    unsigned short* __restrict__ xb, unsigned short* __restrict__ wcat) {
  size_t i4 = (size_t)blockIdx.x * 256 + threadIdx.x;   // one float4 per thread
  const size_t NX4 = (size_t)(B_ * T_ * 512) / 4;       // 2097152
  const float* src; unsigned short* dst; size_t off4;
  if (i4 < NX4) { src = x; dst = xb; off4 = i4; }
  else {
    size_t w4 = i4 - NX4;                 // < 196608
    size_t mat = w4 >> 16;                // 65536 float4 per 512x512 matrix
    off4 = w4 & 65535;
    src = (mat == 0) ? wq : (mat == 1) ? wk : wv;
    dst = wcat + (mat << 18);
  }
  float4 v = ((const float4*)src)[off4];
  unsigned long long pk = (unsigned long long)f2h(v.x)
                        | ((unsigned long long)f2h(v.y) << 16)
                        | ((unsigned long long)f2h(v.z) << 32)
                        | ((unsigned long long)f2h(v.w) << 48);
  *(unsigned long long*)(dst + off4 * 4) = pk;
}

// ---------------------------------------------------------------- QKV GEMM
// (unchanged — verified)
__device__ __forceinline__ void gemm_stage(
    const unsigned short* __restrict__ xb, const unsigned short* __restrict__ wcat,
    char* smem, int buf, int mbase, int nbase, int kt, int wv, int lane, int srcg) {
  char* base = smem + buf * 32768;
  const int kbase = kt * 64;
  if (wv < 2) {
    #pragma unroll
    for (int i = 0; i < 8; ++i) {
      const int blk = wv * 8 + i;
      const int row = blk * 8 + (lane >> 3);
      gload_lds16(xb + (size_t)(mbase + row) * 512 + kbase + srcg, base + blk * 1024);
    }
  } else {
    #pragma unroll
    for (int i = 0; i < 8; ++i) {
      const int blk = (wv - 2) * 8 + i;
      const int row = blk * 8 + (lane >> 3);
      gload_lds16(wcat + (size_t)(nbase + row) * 512 + kbase + srcg, base + 16384 + blk * 1024);
    }
  }
}

__global__ __launch_bounds__(256, 2) void gemm_qkv(
    const unsigned short* __restrict__ xb, const unsigned short* __restrict__ wcat,
    unsigned short* __restrict__ Qb, unsigned short* __restrict__ Kf,
    unsigned short* __restrict__ Vtb) {
  __shared__ char smem[65536];
  const int tid = threadIdx.x, lane = tid & 63, wv = tid >> 6;
  const int wr = wv >> 1, wc = wv & 1;
  const int l15 = lane & 15, l4 = lane >> 4;
  const int mbase = blockIdx.x * 128;
  const int nbase = blockIdx.y * 128;
  const int srcg = (((lane & 7) ^ ((lane >> 3) & 7))) * 8;

  f32x4 acc[4][4];
  #pragma unroll
  for (int i = 0; i < 4; ++i)
    #pragma unroll
    for (int j = 0; j < 4; ++j) acc[i][j] = (f32x4){0.f, 0.f, 0.f, 0.f};

  gemm_stage(xb, wcat, smem, 0, mbase, nbase, 0, wv, lane, srcg);
  for (int kt = 0; kt < 8; ++kt) {
    __syncthreads();
    if (kt < 7) gemm_stage(xb, wcat, smem, (kt + 1) & 1, mbase, nbase, kt + 1, wv, lane, srcg);
    const char* base = smem + (kt & 1) * 32768;
    #pragma unroll
    for (int ks = 0; ks < 2; ++ks) {
      half8 a[4], b8[4];
      #pragma unroll
      for (int rt = 0; rt < 4; ++rt) {
        const int row = wr * 64 + rt * 16 + l15;
        const int G = (ks * 4 + l4) ^ (row & 7);
        a[rt] = *(const half8*)(base + row * 128 + G * 16);
      }
      #pragma unroll
      for (int ct = 0; ct < 4; ++ct) {
        const int row = wc * 64 + ct * 16 + l15;
        const int G = (ks * 4 + l4) ^ (row & 7);
        b8[ct] = *(const half8*)(base + 16384 + row * 128 + G * 16);
      }
      #pragma unroll
      for (int rt = 0; rt < 4; ++rt)
        #pragma unroll
        for (int ct = 0; ct < 4; ++ct)
          acc[rt][ct] = __builtin_amdgcn_mfma_f32_16x16x32_f16(a[rt], b8[ct], acc[rt][ct], 0, 0, 0);
    }
  }

  const int mat = nbase >> 9;          // 0=Q, 1=K, 2=V
  const int nloc = nbase & 511;
  if (mat == 0) {
    #pragma unroll
    for (int rt = 0; rt < 4; ++rt)
      #pragma unroll
      for (int ct = 0; ct < 4; ++ct) {
        const int m0 = mbase + wr * 64 + rt * 16 + l4 * 4;
        const int n = nloc + wc * 64 + ct * 16 + l15;
        #pragma unroll
        for (int j = 0; j < 4; ++j)
          Qb[(size_t)(m0 + j) * 512 + n] = f2h(acc[rt][ct][j]);
      }
  } else if (mat == 1) {
    // K in flash A-frag order
    #pragma unroll
    for (int rt = 0; rt < 4; ++rt)
      #pragma unroll
      for (int ct = 0; ct < 4; ++ct) {
        const int m0 = mbase + wr * 64 + rt * 16 + l4 * 4;
        const int d = nloc + wc * 64 + ct * 16 + l15;
        const int s = d >> 4, hh = (d >> 3) & 1, e = d & 7;
        #pragma unroll
        for (int j = 0; j < 4; ++j) {
          const int t = m0 + j;
          const int bb = t >> 11, tt = t & 2047;
          const size_t blk =
              ((((size_t)bb * 64 + (tt >> 5)) * 32 + s) * 32 + (tt & 31)) * 2 + hh;
          Kf[blk * 8 + e] = f2h(acc[rt][ct][j]);
        }
      }
  } else {
    // V in flash frag order; j..j+3 stay within one 16B block
    #pragma unroll
    for (int rt = 0; rt < 4; ++rt)
      #pragma unroll
      for (int ct = 0; ct < 4; ++ct) {
        const int m0 = mbase + wr * 64 + rt * 16 + l4 * 4;
        const int d = nloc + wc * 64 + ct * 16 + l15;
        const int bb = m0 >> 11, t = m0 & 2047;
        const int kvt = t >> 7, u = (t >> 3) & 15, jj = t & 7;
        unsigned long long pk = (unsigned long long)f2h(acc[rt][ct][0])
                              | ((unsigned long long)f2h(acc[rt][ct][1]) << 16)
                              | ((unsigned long long)f2h(acc[rt][ct][2]) << 32)
                              | ((unsigned long long)f2h(acc[rt][ct][3]) << 48);
        *(unsigned long long*)(Vtb + ((((size_t)bb * 16 + kvt) * 16 + u) * 512 + d) * 8 + jj) = pk;
      }
  }
}

// ---------------------------------------------------------------- flash attention
// Persistent: 512 WGs x 4 waves grab tickets n -> (b = n&7, qt = 63-(n>>3)).
// Per tile: 32 q-rows, nkv = (qt+4)>>2 steps of KVBLK=128 (R8 verified body).
// QK: wave ks=wv: S^T strip = mfma32(kf, Q_lds). PV: d strip [wv*128..+128).
__global__ __launch_bounds__(256, 3) void flash_kernel(
    const unsigned short* __restrict__ Qb, const unsigned short* __restrict__ Kf,
    const unsigned short* __restrict__ Vtb, float* __restrict__ out,
    int* __restrict__ ctr) {
  extern __shared__ char smem[];
  int* tkt = (int*)(smem + FL_TKT);

  const int tid = threadIdx.x, lane = tid & 63, wv = tid >> 6;   // 4 waves
  const int l31 = lane & 31, h = lane >> 5;
  const int ks = wv;                               // QK role: kv strip
  const int qsw = l31 & 7;                         // P swizzle (row&7)

  for (;;) {
    __syncthreads();                               // LDS (Q/scratch/tkt) reusable
    if (tid == 0) *tkt = atomicAdd(ctr, 1);
    __syncthreads();
    const int n = *tkt;
    if (n >= NTILE) break;
    const int b = n & 7;                           // batch (XCD-spread)
    const int qt = 63 - (n >> 3);                  // long tiles first
    const size_t bT = (size_t)b * T_;
    const int nkv = (qt + 4) >> 2;
    const int qmax = qt * 32 + 31;

    // ---- stage Q [32][512]: LDS[r] granule g = Q[r][g ^ (r&31)] ----
    {
      const unsigned short* src = Qb + (bT + (size_t)qt * 32) * 512;
      #pragma unroll
      for (int i = 0; i < 8; ++i) {
        const int r = wv * 8 + i;
        gload_lds16(src + (size_t)r * 512 + ((lane ^ (r & 31)) * 8), smem + r * 1024);
      }
    }
    asm volatile("s_waitcnt vmcnt(0)" ::: "memory");
    __builtin_amdgcn_s_barrier();

    f32x16 o[4];                                   // O^T strip [128 d][32 q]
    #pragma unroll
    for (int dt = 0; dt < 4; ++dt)
      #pragma unroll
      for (int r = 0; r < 16; ++r) o[dt][r] = 0.f;
    float lreg = 0.f, mqpv = -1e30f, mqk = -1e30f;

    for (int kv = 0; kv < nkv; ++kv) {
      const int kv0 = kv * 128;
      const int p = kv & 1;
      char* Pp = smem + FL_P;
      float* stxp = (float*)(smem + FL_STX + p * 512);
      float* stsp = (float*)(smem + FL_STS + p * 512);
      const bool active = (kv0 + ks * 32) <= qmax;

      // ---- K strip -> transient regs (skip if fully masked) ----
      half8 kf[32];
      if (active) {
        const unsigned short* kp =
            Kf + (((size_t)b * 64 + (kv * 4 + ks)) << 14) + l31 * 16 + h * 8;
        #pragma unroll
        for (int s = 0; s < 32; ++s) kf[s] = *(const half8*)(kp + s * 512);
      }

      // ---- QK^T swapped: acc = S^T[32 kv strip][32 q], full D ----
      f32x16 acc;
      #pragma unroll
      for (int r = 0; r < 16; ++r) acc[r] = 0.f;
      if (active) {
        const char* qb = smem + l31 * 1024;
        #pragma unroll
        for (int s = 0; s < 32; ++s) {
          half8 qf = *(const half8*)(qb + (((s * 2 + h) ^ l31) << 4));
          acc = __builtin_amdgcn_mfma_f32_32x32x16_f16(kf[s], qf, acc, 0, 0, 0);
        }
      }

      // ---- V frags half 0 (s=0..3): issued early ----
      const size_t vblk = ((size_t)b * 16 + kv) * 16;
      half8 vf0[4][4];
      #pragma unroll
      for (int s = 0; s < 4; ++s)
        #pragma unroll
        for (int dt = 0; dt < 4; ++dt)
          vf0[s][dt] = *(const half8*)(
              Vtb + ((vblk + s * 2 + h) * 512 + wv * 128 + dt * 32 + l31) * 8);

      // ---- scale + causal mask + in-lane strip max ----
      float v[16], tm = -1e30f;
      const int qglob = qt * 32 + l31;
      #pragma unroll
      for (int r = 0; r < 16; ++r) {
        const int kvg = kv0 + ks * 32 + (r & 3) + 8 * (r >> 2) + 4 * h;
        v[r] = (kvg <= qglob) ? acc[r] * SCALE_ : -1e30f;
        tm = fmaxf(tm, v[r]);
      }
      tm = fmaxf(tm, __shfl_xor(tm, 32, 64));
      if (h == 0) stxp[l31 * 4 + ks] = tm;
      barrier_lgkm();                              // B: strip maxes visible

      // ---- softmax (per-lane scalar state) ----
      {
        const f32x4 sx = *(const f32x4*)(stxp + l31 * 4);
        const float mn = fmaxf(fmaxf(fmaxf(sx[0], sx[1]), fmaxf(sx[2], sx[3])), mqk);
        mqk = mn;
        unsigned short ph[16];
        float ps = 0.f;
        #pragma unroll
        for (int r = 0; r < 16; ++r) {
          const float pv = __expf(v[r] - mn);
          ph[r] = f2h(pv);                         // round first; sum the rounded
          ps += (float)*(const _Float16*)&ph[r];
        }
        ps += __shfl_xor(ps, 32, 64);
        if (h == 0) stsp[l31 * 4 + ks] = ps;
        #pragma unroll
        for (int c = 0; c < 4; ++c) {              // P -> LDS, b64 packed
          const unsigned long long pk =
              (unsigned long long)ph[4 * c]
            | ((unsigned long long)ph[4 * c + 1] << 16)
            | ((unsigned long long)ph[4 * c + 2] << 32)
            | ((unsigned long long)ph[4 * c + 3] << 48);
          *(unsigned long long*)(Pp + l31 * 256 +
                                 ((((ks * 4 + c) ^ qsw)) << 4) + h * 8) = pk;
        }
      }
      barrier_lgkm();                              // C: P + stats visible

      // ---- per-lane alpha/l update, rescale O ----
      {
        const f32x4 sx2 = *(const f32x4*)(stxp + l31 * 4);
        float mn2 = fmaxf(fmaxf(sx2[0], sx2[1]), fmaxf(sx2[2], sx2[3]));
        mn2 = fmaxf(mn2, mqpv);
        const float a = __expf(mqpv - mn2);
        mqpv = mn2;
        const f32x4 s4 = *(const f32x4*)(stsp + l31 * 4);
        lreg = a * lreg + ((s4[0] + s4[1]) + (s4[2] + s4[3]));
        #pragma unroll
        for (int dt = 0; dt < 4; ++dt)
          #pragma unroll
          for (int r = 0; r < 16; ++r) o[dt][r] *= a;
      }

      // ---- V frags half 1 (s=4..7) ----
      half8 vf1[4][4];
      #pragma unroll
      for (int s = 0; s < 4; ++s)
        #pragma unroll
        for (int dt = 0; dt < 4; ++dt)
          vf1[s][dt] = *(const half8*)(
              Vtb + ((vblk + (s + 4) * 2 + h) * 512 + wv * 128 + dt * 32 + l31) * 8);

      // ---- PV: O^T += Vt x P ----
      #pragma unroll
      for (int s = 0; s < 8; ++s) {
        const half8 pa = *(const half8*)(Pp + l31 * 256 + (((s * 2 + h) ^ qsw) << 4));
        #pragma unroll
        for (int dt = 0; dt < 4; ++dt) {
          const half8 vfr = (s < 4) ? vf0[s][dt] : vf1[s - 4][dt];
          o[dt] = __builtin_amdgcn_mfma_f32_32x32x16_f16(vfr, pa, o[dt], 0, 0, 0);
        }
      }
    }

    // ---- epilogue: transpose O^T via per-wave scratch (Q region dead), ----
    // ---- divide by l, coalesced stores ----
    {
      char* scr = smem + wv * 4608;                // 32 rows x 144B
      const float linv = 1.0f / lreg;
      #pragma unroll
      for (int dt = 0; dt < 4; ++dt) {
        #pragma unroll
        for (int c = 0; c < 4; ++c) {
          f32x4 w4;
          #pragma unroll
          for (int j = 0; j < 4; ++j) w4[j] = o[dt][4 * c + j] * linv;
          *(f32x4*)(scr + l31 * 144 + c * 32 + h * 16) = w4;   // scr[q][d]
        }
        asm volatile("s_waitcnt lgkmcnt(0)" ::: "memory");
        #pragma unroll
        for (int g = 0; g < 4; ++g) {
          const int qr = g * 8 + (lane >> 3);
          const f32x4 r4 = *(const f32x4*)(scr + qr * 144 + (lane & 7) * 16);
          *(f32x4*)(out + (bT + qt * 32 + qr) * 512 +
                    wv * 128 + dt * 32 + (lane & 7) * 4) = r4;
        }
        asm volatile("s_waitcnt lgkmcnt(0)" ::: "memory");
      }
    }
  }
}

// ---------------------------------------------------------------- launch
extern "C" void kernel_launch(void* const* d_in, const int* in_sizes, int n_in,
                              void* d_out, int out_size, void* d_ws, size_t ws_size,
                              hipStream_t stream) {
  (void)in_sizes; (void)n_in; (void)out_size; (void)ws_size;
  const float* x  = (const float*)d_in[0];
  const float* wq = (const float*)d_in[1];
  const float* wk = (const float*)d_in[2];
  const float* wv = (const float*)d_in[3];
  float* out = (float*)d_out;

  unsigned short* ws   = (unsigned short*)d_ws;
  unsigned short* xb   = ws;                                    // [16384][512]
  unsigned short* wcat = xb + (size_t)16384 * 512;              // [1536][512]
  unsigned short* Qb   = wcat + (size_t)1536 * 512;             // [16384][512] row-major
  unsigned short* Kf   = Qb + (size_t)16384 * 512;              // [8][64][32][32][2][8] frag order
  unsigned short* Vtb  = Kf + (size_t)16384 * 512;              // [8][16][16][512][8] frag order
  int* ctr = (int*)(Vtb + (size_t)16384 * 512);                 // ticket counter
  // total ws use: 68.7 MB + 4B

  hipMemsetAsync(ctr, 0, 4, stream);
  cast_kernel<<<8960, 256, 0, stream>>>(x, wq, wk, wv, xb, wcat);
  gemm_qkv<<<dim3(128, 12), 256, 0, stream>>>(xb, wcat, Qb, Kf, Vtb);
  hipFuncSetAttribute(reinterpret_cast<const void*>(flash_kernel),
                      hipFuncAttributeMaxDynamicSharedMemorySize, FL_SMEM);
  flash_kernel<<<512, 256, FL_SMEM, stream>>>(Qb, Kf, Vtb, out, ctr);
}

// Round 12
// 117.631 us; speedup vs baseline: 4.5296x; 4.5296x over previous
//
#include <hip/hip_runtime.h>

// MHAttention B=8 T=2048 C=512 H=512, causal, fp32 in/out.
// cast(fp32->fp16) -> fused QKV GEMM (Q row-major; K,V in MFMA-frag order) -> flash.
// R12 flash: 512 WGs x 8 waves, 32-row q-tiles, KVBLK=256 (8 strips = 8 waves).
// Per-wave per-step work identical to R7 (verified 97us / 96 VGPR / no spills):
// unconditional JIT kf loads, transient vf chunks <=32 VGPR, per-lane softmax.
// Longest WG: 8 steps (was 16). 2-deep WG scheduling backfills short tiles.

using short8 = __attribute__((ext_vector_type(8))) short;
using half8  = __attribute__((ext_vector_type(8))) _Float16;
using f32x4  = __attribute__((ext_vector_type(4))) float;
using f32x16 = __attribute__((ext_vector_type(16))) float;

#define B_    8
#define T_    2048
#define SCALE_ 0.044194173824159216f   // 512^-0.5

// flash LDS: Q [32 rows][1KB] f16 (16B-granule XOR row&31) at 0
#define FL_P    32768    // [32 q][512B] f16 (granule XOR row&7), single buffer
#define FL_STX  49152    // 2 x [32 q][8 ks] f32 (step parity)
#define FL_STS  51200    // 2 x [32 q][8 ks] f32
#define FL_SMEM 53248
// epilogue scratch (post-barrier) reuses Q+P regions: wave wv at wv*4608 (<=36864)

__device__ __forceinline__ void gload_lds16(const void* g, void* l) {
  __builtin_amdgcn_global_load_lds(
      (const __attribute__((address_space(1))) unsigned int*)g,
      (__attribute__((address_space(3))) unsigned int*)l, 16, 0, 0);
}

__device__ __forceinline__ unsigned short f2h(float f) {  // RNE f32->f16 bits
  _Float16 h = (_Float16)f;
  return *(unsigned short*)&h;
}

// barrier waiting only on LDS ops — global loads (vmcnt) stay in flight
__device__ __forceinline__ void barrier_lgkm() {
  asm volatile("s_waitcnt lgkmcnt(0)" ::: "memory");
  __builtin_amdgcn_s_barrier();
  asm volatile("" ::: "memory");
}

// ---------------------------------------------------------------- cast kernel
__global__ __launch_bounds__(256) void cast_kernel(
    const float* __restrict__ x, const float* __restrict__ wq,
    const float* __restrict__ wk, const float* __restrict__ wv,
    unsigned short* __restrict__ xb, unsigned short* __restrict__ wcat) {
  size_t i4 = (size_t)blockIdx.x * 256 + threadIdx.x;   // one float4 per thread
  const size_t NX4 = (size_t)(B_ * T_ * 512) / 4;       // 2097152
  const float* src; unsigned short* dst; size_t off4;
  if (i4 < NX4) { src = x; dst = xb; off4 = i4; }
  else {
    size_t w4 = i4 - NX4;                 // < 196608
    size_t mat = w4 >> 16;                // 65536 float4 per 512x512 matrix
    off4 = w4 & 65535;
    src = (mat == 0) ? wq : (mat == 1) ? wk : wv;
    dst = wcat + (mat << 18);
  }
  float4 v = ((const float4*)src)[off4];
  unsigned long long pk = (unsigned long long)f2h(v.x)
                        | ((unsigned long long)f2h(v.y) << 16)
                        | ((unsigned long long)f2h(v.z) << 32)
                        | ((unsigned long long)f2h(v.w) << 48);
  *(unsigned long long*)(dst + off4 * 4) = pk;
}

// ---------------------------------------------------------------- QKV GEMM
// (unchanged — verified; K/V layouts consumed by flash are identical)
__device__ __forceinline__ void gemm_stage(
    const unsigned short* __restrict__ xb, const unsigned short* __restrict__ wcat,
    char* smem, int buf, int mbase, int nbase, int kt, int wv, int lane, int srcg) {
  char* base = smem + buf * 32768;
  const int kbase = kt * 64;
  if (wv < 2) {
    #pragma unroll
    for (int i = 0; i < 8; ++i) {
      const int blk = wv * 8 + i;
      const int row = blk * 8 + (lane >> 3);
      gload_lds16(xb + (size_t)(mbase + row) * 512 + kbase + srcg, base + blk * 1024);
    }
  } else {
    #pragma unroll
    for (int i = 0; i < 8; ++i) {
      const int blk = (wv - 2) * 8 + i;
      const int row = blk * 8 + (lane >> 3);
      gload_lds16(wcat + (size_t)(nbase + row) * 512 + kbase + srcg, base + 16384 + blk * 1024);
    }
  }
}

__global__ __launch_bounds__(256, 2) void gemm_qkv(
    const unsigned short* __restrict__ xb, const unsigned short* __restrict__ wcat,
    unsigned short* __restrict__ Qb, unsigned short* __restrict__ Kf,
    unsigned short* __restrict__ Vtb) {
  __shared__ char smem[65536];
  const int tid = threadIdx.x, lane = tid & 63, wv = tid >> 6;
  const int wr = wv >> 1, wc = wv & 1;
  const int l15 = lane & 15, l4 = lane >> 4;
  const int mbase = blockIdx.x * 128;
  const int nbase = blockIdx.y * 128;
  const int srcg = (((lane & 7) ^ ((lane >> 3) & 7))) * 8;

  f32x4 acc[4][4];
  #pragma unroll
  for (int i = 0; i < 4; ++i)
    #pragma unroll
    for (int j = 0; j < 4; ++j) acc[i][j] = (f32x4){0.f, 0.f, 0.f, 0.f};

  gemm_stage(xb, wcat, smem, 0, mbase, nbase, 0, wv, lane, srcg);
  for (int kt = 0; kt < 8; ++kt) {
    __syncthreads();
    if (kt < 7) gemm_stage(xb, wcat, smem, (kt + 1) & 1, mbase, nbase, kt + 1, wv, lane, srcg);
    const char* base = smem + (kt & 1) * 32768;
    #pragma unroll
    for (int ks = 0; ks < 2; ++ks) {
      half8 a[4], b8[4];
      #pragma unroll
      for (int rt = 0; rt < 4; ++rt) {
        const int row = wr * 64 + rt * 16 + l15;
        const int G = (ks * 4 + l4) ^ (row & 7);
        a[rt] = *(const half8*)(base + row * 128 + G * 16);
      }
      #pragma unroll
      for (int ct = 0; ct < 4; ++ct) {
        const int row = wc * 64 + ct * 16 + l15;
        const int G = (ks * 4 + l4) ^ (row & 7);
        b8[ct] = *(const half8*)(base + 16384 + row * 128 + G * 16);
      }
      #pragma unroll
      for (int rt = 0; rt < 4; ++rt)
        #pragma unroll
        for (int ct = 0; ct < 4; ++ct)
          acc[rt][ct] = __builtin_amdgcn_mfma_f32_16x16x32_f16(a[rt], b8[ct], acc[rt][ct], 0, 0, 0);
    }
  }

  const int mat = nbase >> 9;          // 0=Q, 1=K, 2=V
  const int nloc = nbase & 511;
  if (mat == 0) {
    #pragma unroll
    for (int rt = 0; rt < 4; ++rt)
      #pragma unroll
      for (int ct = 0; ct < 4; ++ct) {
        const int m0 = mbase + wr * 64 + rt * 16 + l4 * 4;
        const int n = nloc + wc * 64 + ct * 16 + l15;
        #pragma unroll
        for (int j = 0; j < 4; ++j)
          Qb[(size_t)(m0 + j) * 512 + n] = f2h(acc[rt][ct][j]);
      }
  } else if (mat == 1) {
    // K in flash A-frag order
    #pragma unroll
    for (int rt = 0; rt < 4; ++rt)
      #pragma unroll
      for (int ct = 0; ct < 4; ++ct) {
        const int m0 = mbase + wr * 64 + rt * 16 + l4 * 4;
        const int d = nloc + wc * 64 + ct * 16 + l15;
        const int s = d >> 4, hh = (d >> 3) & 1, e = d & 7;
        #pragma unroll
        for (int j = 0; j < 4; ++j) {
          const int t = m0 + j;
          const int bb = t >> 11, tt = t & 2047;
          const size_t blk =
              ((((size_t)bb * 64 + (tt >> 5)) * 32 + s) * 32 + (tt & 31)) * 2 + hh;
          Kf[blk * 8 + e] = f2h(acc[rt][ct][j]);
        }
      }
  } else {
    // V in flash frag order; j..j+3 stay within one 16B block
    #pragma unroll
    for (int rt = 0; rt < 4; ++rt)
      #pragma unroll
      for (int ct = 0; ct < 4; ++ct) {
        const int m0 = mbase + wr * 64 + rt * 16 + l4 * 4;
        const int d = nloc + wc * 64 + ct * 16 + l15;
        const int bb = m0 >> 11, t = m0 & 2047;
        const int kvt = t >> 7, u = (t >> 3) & 15, jj = t & 7;
        unsigned long long pk = (unsigned long long)f2h(acc[rt][ct][0])
                              | ((unsigned long long)f2h(acc[rt][ct][1]) << 16)
                              | ((unsigned long long)f2h(acc[rt][ct][2]) << 32)
                              | ((unsigned long long)f2h(acc[rt][ct][3]) << 48);
        *(unsigned long long*)(Vtb + ((((size_t)bb * 16 + kvt) * 16 + u) * 512 + d) * 8 + jj) = pk;
      }
  }
}

// ---------------------------------------------------------------- flash attention
// 512 WGs x 8 waves; b = blk&7 (XCD), qt = 63-(blk>>3) (32 q-rows, long first).
// nkv = (qt+8)>>3 steps of KVBLK=256 (max 8).
// QK: wave ks=wv: S^T strip = mfma32(kf[kv*8+ks], Q_lds), full D. Softmax state
// per-lane scalar (q = l31). PV: wave owns d strip [wv*64..+64).
// Per step (parity p): kf JIT -> QK -> vfA chunk -> mask/max -> stx[p] -> lgkmB
//   -> softmax -> P+sts[p] -> lgkmC -> rescale -> PV (4 vf chunks of 32 VGPR).
__global__ __launch_bounds__(512, 1) void flash_kernel(
    const unsigned short* __restrict__ Qb, const unsigned short* __restrict__ Kf,
    const unsigned short* __restrict__ Vtb, float* __restrict__ out) {
  extern __shared__ char smem[];

  const int tid = threadIdx.x, lane = tid & 63, wv = tid >> 6;   // 8 waves
  const int l31 = lane & 31, h = lane >> 5;
  const int ks = wv;                               // QK role: kv strip 0..7
  const int qsw = l31 & 7;                         // P swizzle (row&7)
  const int b = blockIdx.x & 7;                    // batch == XCD
  const int qt = 63 - (blockIdx.x >> 3);           // long tiles first
  const size_t bT = (size_t)b * T_;
  const int nkv = (qt + 8) >> 3;

  // ---- stage Q [32][512] once: LDS[r] granule g = Q[r][g ^ (r&31)] ----
  {
    const unsigned short* src = Qb + (bT + (size_t)qt * 32) * 512;
    #pragma unroll
    for (int i = 0; i < 4; ++i) {
      const int r = wv * 4 + i;
      gload_lds16(src + (size_t)r * 512 + ((lane ^ (r & 31)) * 8), smem + r * 1024);
    }
  }
  asm volatile("s_waitcnt vmcnt(0)" ::: "memory");
  __builtin_amdgcn_s_barrier();

  f32x16 o[2];                                     // O^T [64 d][32 q], dt tiles
  #pragma unroll
  for (int dt = 0; dt < 2; ++dt)
    #pragma unroll
    for (int r = 0; r < 16; ++r) o[dt][r] = 0.f;
  float lreg = 0.f, mqpv = -1e30f, mqk = -1e30f;

  for (int kv = 0; kv < nkv; ++kv) {
    const int kv0 = kv * 256;
    const int p = kv & 1;
    char* Pp = smem + FL_P;
    float* stxp = (float*)(smem + FL_STX + p * 1024);
    float* stsp = (float*)(smem + FL_STS + p * 1024);

    // ---- K strip -> transient regs (unconditional; R7's proven JIT form) ----
    half8 kf[32];
    {
      const unsigned short* kp =
          Kf + (((size_t)b * 64 + (kv * 8 + ks)) << 14) + l31 * 16 + h * 8;
      #pragma unroll
      for (int s = 0; s < 32; ++s) kf[s] = *(const half8*)(kp + s * 512);
    }

    // ---- QK^T swapped: acc = S^T[32 kv strip][32 q], full D ----
    f32x16 acc;
    #pragma unroll
    for (int r = 0; r < 16; ++r) acc[r] = 0.f;
    {
      const char* qb = smem + l31 * 1024;
      #pragma unroll
      for (int s = 0; s < 32; ++s) {
        half8 qf = *(const half8*)(qb + (((s * 2 + h) ^ l31) << 4));
        acc = __builtin_amdgcn_mfma_f32_32x32x16_f16(kf[s], qf, acc, 0, 0, 0);
      }
    }

    // ---- vf chunk 0 (kvt=2kv, u=0..7): issued early, consumed post-C ----
    half8 vfA[4][2];
    {
      const size_t vblk = ((size_t)b * 16 + kv * 2) * 16;
      #pragma unroll
      for (int s4 = 0; s4 < 4; ++s4)
        #pragma unroll
        for (int dt = 0; dt < 2; ++dt)
          vfA[s4][dt] = *(const half8*)(
              Vtb + ((vblk + s4 * 2 + h) * 512 + wv * 64 + dt * 32 + l31) * 8);
    }

    // ---- scale + causal mask + in-lane strip max ----
    float v[16], tm = -1e30f;
    const int qglob = qt * 32 + l31;
    #pragma unroll
    for (int r = 0; r < 16; ++r) {
      const int kvg = kv0 + ks * 32 + (r & 3) + 8 * (r >> 2) + 4 * h;
      v[r] = (kvg <= qglob) ? acc[r] * SCALE_ : -1e30f;
      tm = fmaxf(tm, v[r]);
    }
    tm = fmaxf(tm, __shfl_xor(tm, 32, 64));
    if (h == 0) stxp[l31 * 8 + ks] = tm;
    barrier_lgkm();                                // B: strip maxes visible

    // ---- softmax (per-lane scalar state, q = l31) ----
    {
      const f32x4 sxa = *(const f32x4*)(stxp + l31 * 8);
      const f32x4 sxb = *(const f32x4*)(stxp + l31 * 8 + 4);
      float mn = fmaxf(fmaxf(fmaxf(sxa[0], sxa[1]), fmaxf(sxa[2], sxa[3])),
                       fmaxf(fmaxf(sxb[0], sxb[1]), fmaxf(sxb[2], sxb[3])));
      mn = fmaxf(mn, mqk);
      mqk = mn;
      unsigned short ph[16];
      float ps = 0.f;
      #pragma unroll
      for (int r = 0; r < 16; ++r) {
        const float pv = __expf(v[r] - mn);
        ph[r] = f2h(pv);                           // round first; sum the rounded
        ps += (float)*(const _Float16*)&ph[r];
      }
      ps += __shfl_xor(ps, 32, 64);
      if (h == 0) stsp[l31 * 8 + ks] = ps;
      #pragma unroll
      for (int c = 0; c < 4; ++c) {                // P -> LDS, b64 packed
        const unsigned long long pk =
            (unsigned long long)ph[4 * c]
          | ((unsigned long long)ph[4 * c + 1] << 16)
          | ((unsigned long long)ph[4 * c + 2] << 32)
          | ((unsigned long long)ph[4 * c + 3] << 48);
        *(unsigned long long*)(Pp + l31 * 512 +
                               ((((ks * 4 + c) ^ qsw)) << 4) + h * 8) = pk;
      }
    }
    barrier_lgkm();                                // C: P + stats visible

    // ---- per-lane alpha/l update, rescale O ----
    {
      const f32x4 sxa = *(const f32x4*)(stxp + l31 * 8);
      const f32x4 sxb = *(const f32x4*)(stxp + l31 * 8 + 4);
      float mn2 = fmaxf(fmaxf(fmaxf(sxa[0], sxa[1]), fmaxf(sxa[2], sxa[3])),
                        fmaxf(fmaxf(sxb[0], sxb[1]), fmaxf(sxb[2], sxb[3])));
      mn2 = fmaxf(mn2, mqpv);
      const float a = __expf(mqpv - mn2);
      mqpv = mn2;
      const f32x4 s4a = *(const f32x4*)(stsp + l31 * 8);
      const f32x4 s4b = *(const f32x4*)(stsp + l31 * 8 + 4);
      lreg = a * lreg +
             (((s4a[0] + s4a[1]) + (s4a[2] + s4a[3])) +
              ((s4b[0] + s4b[1]) + (s4b[2] + s4b[3])));
      #pragma unroll
      for (int dt = 0; dt < 2; ++dt)
        #pragma unroll
        for (int r = 0; r < 16; ++r) o[dt][r] *= a;
    }

    // ---- PV: O^T += Vt x P over 256 kv, 4 chunks of 4 s (vf <=32 VGPR) ----
    #pragma unroll
    for (int ch = 0; ch < 4; ++ch) {
      half8 vf[4][2];
      if (ch == 0) {
        #pragma unroll
        for (int s4 = 0; s4 < 4; ++s4)
          #pragma unroll
          for (int dt = 0; dt < 2; ++dt) vf[s4][dt] = vfA[s4][dt];
      } else {
        const size_t vblk = ((size_t)b * 16 + kv * 2 + (ch >> 1)) * 16;
        #pragma unroll
        for (int s4 = 0; s4 < 4; ++s4)
          #pragma unroll
          for (int dt = 0; dt < 2; ++dt)
            vf[s4][dt] = *(const half8*)(
                Vtb + ((vblk + ((ch & 1) * 4 + s4) * 2 + h) * 512 + wv * 64 + dt * 32 + l31) * 8);
      }
      #pragma unroll
      for (int s4 = 0; s4 < 4; ++s4) {
        const int S = ch * 4 + s4;                 // kv 16-chunk index 0..15
        const half8 pa = *(const half8*)(Pp + l31 * 512 +
                                         (((S * 2 + h) ^ qsw) << 4));
        #pragma unroll
        for (int dt = 0; dt < 2; ++dt)
          o[dt] = __builtin_amdgcn_mfma_f32_32x32x16_f16(vf[s4][dt], pa, o[dt], 0, 0, 0);
      }
    }
  }

  barrier_lgkm();                                  // all PV P-reads done (scratch reuse)

  // ---- epilogue: transpose O^T via per-wave scratch, /l, coalesced stores ----
  {
    char* scr = smem + wv * 4608;                  // 32 rows x 144B
    const float linv = 1.0f / lreg;
    #pragma unroll
    for (int dt = 0; dt < 2; ++dt) {
      #pragma unroll
      for (int c = 0; c < 4; ++c) {
        f32x4 w4;
        #pragma unroll
        for (int j = 0; j < 4; ++j) w4[j] = o[dt][4 * c + j] * linv;
        *(f32x4*)(scr + l31 * 144 + c * 32 + h * 16) = w4;   // scr[q][d]
      }
      asm volatile("s_waitcnt lgkmcnt(0)" ::: "memory");
      #pragma unroll
      for (int g = 0; g < 4; ++g) {
        const int qr = g * 8 + (lane >> 3);
        const f32x4 r4 = *(const f32x4*)(scr + qr * 144 + (lane & 7) * 16);
        *(f32x4*)(out + (bT + qt * 32 + qr) * 512 +
                  wv * 64 + dt * 32 + (lane & 7) * 4) = r4;
      }
      asm volatile("s_waitcnt lgkmcnt(0)" ::: "memory");
    }
  }
}

// ---------------------------------------------------------------- launch
extern "C" void kernel_launch(void* const* d_in, const int* in_sizes, int n_in,
                              void* d_out, int out_size, void* d_ws, size_t ws_size,
                              hipStream_t stream) {
  (void)in_sizes; (void)n_in; (void)out_size; (void)ws_size;
  const float* x  = (const float*)d_in[0];
  const float* wq = (const float*)d_in[1];
  const float* wk = (const float*)d_in[2];
  const float* wv = (const float*)d_in[3];
  float* out = (float*)d_out;

  unsigned short* ws   = (unsigned short*)d_ws;
  unsigned short* xb   = ws;                                    // [16384][512]
  unsigned short* wcat = xb + (size_t)16384 * 512;              // [1536][512]
  unsigned short* Qb   = wcat + (size_t)1536 * 512;             // [16384][512] row-major
  unsigned short* Kf   = Qb + (size_t)16384 * 512;              // [8][64][32][32][2][8] frag order
  unsigned short* Vtb  = Kf + (size_t)16384 * 512;              // [8][16][16][512][8] frag order
  // total ws use: 68.7 MB

  cast_kernel<<<8960, 256, 0, stream>>>(x, wq, wk, wv, xb, wcat);
  gemm_qkv<<<dim3(128, 12), 256, 0, stream>>>(xb, wcat, Qb, Kf, Vtb);
  hipFuncSetAttribute(reinterpret_cast<const void*>(flash_kernel),
                      hipFuncAttributeMaxDynamicSharedMemorySize, FL_SMEM);
  flash_kernel<<<512, 512, FL_SMEM, stream>>>(Qb, Kf, Vtb, out);
}